// Round 18
// baseline (119.265 us; speedup 1.0000x reference)
//
#include <hip/hip_runtime.h>

#define NB 8
#define SS 2048
#define HH 512
#define NSTY 128
#define SP (SS + 2)
#define EPSF 1e-5f

#define BM 128
#define BN 128
#define BK 64

typedef __attribute__((ext_vector_type(8))) short short8;
typedef __attribute__((ext_vector_type(4))) float floatx4;
typedef __attribute__((ext_vector_type(4))) unsigned short u16x4;
typedef unsigned short u16;

__device__ __forceinline__ float bf2f(u16 u) {
  union { float f; unsigned int i; } v; v.i = ((unsigned int)u) << 16; return v.f;
}
__device__ __forceinline__ u16 f2bf(float f) {
  union { float f; unsigned int i; } v; v.f = f;
  unsigned int x = v.i;
  return (u16)((x + 0x7fffu + ((x >> 16) & 1u)) >> 16);
}
__device__ __forceinline__ float lrelu(float v) { return v >= 0.f ? v : 0.2f * v; }

__device__ __forceinline__ void gld_lds16(const u16* g, u16* l) {
  __builtin_amdgcn_global_load_lds((const __attribute__((address_space(1))) void*)g,
                                   (__attribute__((address_space(3))) void*)l, 16, 0, 0);
}

// ---------------- fused setup: wnorm | proj | zero stats ----------------
__global__ void k_setup(const float* __restrict__ style,
                        const float* __restrict__ p1w, const float* __restrict__ p1b,
                        const float* __restrict__ p2w, const float* __restrict__ p2b,
                        const float* __restrict__ c1v, const float* __restrict__ c1g,
                        const float* __restrict__ c2v, const float* __restrict__ c2g,
                        u16* __restrict__ wt1, u16* __restrict__ wt2,
                        float* __restrict__ g1, float* __restrict__ be1,
                        float* __restrict__ g2, float* __restrict__ be2,
                        float* __restrict__ stats /* sum1 base, 4*NB*HH contig */) {
  int bid = blockIdx.x;
  if (bid < 2 * HH) {
    int o = bid % HH;
    int which = bid / HH;
    const float* v = which ? c2v : c1v;
    const float* g = which ? c2g : c1g;
    u16* wt = which ? wt2 : wt1;
    float s = 0.f;
    for (int e = threadIdx.x; e < HH * 3; e += 256) {
      float x = v[o * HH * 3 + e];
      s += x * x;
    }
    for (int off = 32; off > 0; off >>= 1) s += __shfl_down(s, off, 64);
    __shared__ float red[4];
    int wid = threadIdx.x >> 6, lane = threadIdx.x & 63;
    if (lane == 0) red[wid] = s;
    __syncthreads();
    float tot = red[0] + red[1] + red[2] + red[3];
    float scale = g[o] / sqrtf(tot);
    for (int e = threadIdx.x; e < HH * 3; e += 256) {
      int i = e / 3, k = e % 3;      // v[o][i][k] flat = o*1536 + e
      wt[(k * HH + o) * HH + i] = f2bf(v[o * HH * 3 + e] * scale);
    }
  } else if (bid < 2 * HH + 64) {
    int idx = (bid - 2 * HH) * 256 + threadIdx.x;
    int which = idx / (NB * 2 * HH);
    int r = idx % (NB * 2 * HH);
    int b = r / (2 * HH);
    int j = r % (2 * HH);
    const float* w = which ? p2w : p1w;
    const float* bias = which ? p2b : p1b;
    float acc = bias[j];
    const float* st = style + b * NSTY;
    const float* wr = w + j * NSTY;
    for (int t = 0; t < NSTY; t++) acc += st[t] * wr[t];
    float* gd = which ? g2 : g1;
    float* bd = which ? be2 : be1;
    if (j < HH) gd[b * HH + j] = acc;
    else        bd[b * HH + (j - HH)] = acc;
  } else {
    int i = (bid - 2 * HH - 64) * 256 + threadIdx.x;
    stats[i] = 0.f;
  }
}

// ---------------- masked stats over S (f32 input), latency-fixed ----------------
#define SSPLIT1 64
__global__ void k_stats_f32(const float* __restrict__ x, const int* __restrict__ lens,
                            float* __restrict__ sum, float* __restrict__ sumsq) {
  int b = blockIdx.x & 7;
  int chunk = blockIdx.x >> 3;                     // 0..63
  int s0 = chunk * (SS / SSPLIT1);                 // 32 rows per block
  int h4 = (threadIdx.x & 127) * 4;                // float4 column
  int sr = threadIdx.x >> 7;                       // 0,1
  int len = lens[b];
  float4 sm = {0.f, 0.f, 0.f, 0.f}, sq = {0.f, 0.f, 0.f, 0.f};
#pragma unroll
  for (int i = 0; i < 16; i++) {
    int s = s0 + i * 2 + sr;
    float4 v = *(const float4*)(x + ((long)(b * SS + s)) * HH + h4);
    float m = (s < len) ? 1.f : 0.f;
    v.x *= m; v.y *= m; v.z *= m; v.w *= m;
    sm.x += v.x; sm.y += v.y; sm.z += v.z; sm.w += v.w;
    sq.x += v.x * v.x; sq.y += v.y * v.y; sq.z += v.z * v.z; sq.w += v.w * v.w;
  }
  atomicAdd(&sum[b * HH + h4 + 0], sm.x);
  atomicAdd(&sum[b * HH + h4 + 1], sm.y);
  atomicAdd(&sum[b * HH + h4 + 2], sm.z);
  atomicAdd(&sum[b * HH + h4 + 3], sm.w);
  atomicAdd(&sumsq[b * HH + h4 + 0], sq.x);
  atomicAdd(&sumsq[b * HH + h4 + 1], sq.y);
  atomicAdd(&sumsq[b * HH + h4 + 2], sq.z);
  atomicAdd(&sumsq[b * HH + h4 + 3], sq.w);
}

// ---------------- Z prep (f32 src), LDS affine table, XCD-aligned ------------
__global__ void k_prep_f32(const float* __restrict__ x,
                           const float* __restrict__ sum, const float* __restrict__ sumsq,
                           const float* __restrict__ gam, const float* __restrict__ bet,
                           const int* __restrict__ lens, u16* __restrict__ z) {
  __shared__ float a_tab[HH], c_tab[HH];
  int b = blockIdx.x & 7;
  int c = blockIdx.x >> 3;                 // row-pair index 0..1024
  int len = lens[b];
  {
    float rc = 1.f / (float)len;
    int i0 = threadIdx.x * 2;
    float2 sm = *(const float2*)(sum + b * HH + i0);
    float2 sq = *(const float2*)(sumsq + b * HH + i0);
    float2 gv = *(const float2*)(gam + b * HH + i0);
    float2 bv = *(const float2*)(bet + b * HH + i0);
    float m0 = sm.x * rc, m1 = sm.y * rc;
    float a0 = (1.f + gv.x) * rsqrtf(sq.x * rc - m0 * m0 + EPSF);
    float a1 = (1.f + gv.y) * rsqrtf(sq.y * rc - m1 * m1 + EPSF);
    a_tab[i0] = a0;            a_tab[i0 + 1] = a1;
    c_tab[i0] = bv.x - m0 * a0; c_tab[i0 + 1] = bv.y - m1 * a1;
  }
  __syncthreads();
  int r = c * 2 + (threadIdx.x >> 7);      // 0..SP-1
  int i = (threadIdx.x & 127) * 4;
  int s = r - 1;
  u16x4 outv;
  if (s < 0 || s >= SS || s >= len) {
    outv = (u16x4){0, 0, 0, 0};
  } else {
    const float4 xv = *(const float4*)(x + ((long)(b * SS + s)) * HH + i);
    const float4 av = *(const float4*)(&a_tab[i]);
    const float4 cv = *(const float4*)(&c_tab[i]);
    outv.x = f2bf(lrelu(av.x * xv.x + cv.x));
    outv.y = f2bf(lrelu(av.y * xv.y + cv.y));
    outv.z = f2bf(lrelu(av.z * xv.z + cv.z));
    outv.w = f2bf(lrelu(av.w * xv.w + cv.w));
  }
  *(u16x4*)(z + ((long)(b * SP + r)) * HH + i) = outv;
}

// ---------------- Z prep (bf16 src), LDS affine table, XCD-aligned -----------
__global__ void k_prep_bf16(const u16* __restrict__ y,
                            const float* __restrict__ sum, const float* __restrict__ sumsq,
                            const float* __restrict__ gam, const float* __restrict__ bet,
                            const int* __restrict__ lens, u16* __restrict__ z) {
  __shared__ float a_tab[HH], c_tab[HH];
  int b = blockIdx.x & 7;
  int c = blockIdx.x >> 3;
  int len = lens[b];
  {
    float rc = 1.f / (float)len;
    int i0 = threadIdx.x * 2;
    float2 sm = *(const float2*)(sum + b * HH + i0);
    float2 sq = *(const float2*)(sumsq + b * HH + i0);
    float2 gv = *(const float2*)(gam + b * HH + i0);
    float2 bv = *(const float2*)(bet + b * HH + i0);
    float m0 = sm.x * rc, m1 = sm.y * rc;
    float a0 = (1.f + gv.x) * rsqrtf(sq.x * rc - m0 * m0 + EPSF);
    float a1 = (1.f + gv.y) * rsqrtf(sq.y * rc - m1 * m1 + EPSF);
    a_tab[i0] = a0;            a_tab[i0 + 1] = a1;
    c_tab[i0] = bv.x - m0 * a0; c_tab[i0 + 1] = bv.y - m1 * a1;
  }
  __syncthreads();
  int r = c * 2 + (threadIdx.x >> 7);
  int i = (threadIdx.x & 127) * 4;
  int s = r - 1;
  u16x4 outv;
  if (s < 0 || s >= SS || s >= len) {
    outv = (u16x4){0, 0, 0, 0};
  } else {
    const u16x4 yv = *(const u16x4*)(y + ((long)(b * SS + s)) * HH + i);
    const float4 av = *(const float4*)(&a_tab[i]);
    const float4 cv = *(const float4*)(&c_tab[i]);
    outv.x = f2bf(lrelu(av.x * bf2f(yv.x) + cv.x));
    outv.y = f2bf(lrelu(av.y * bf2f(yv.y) + cv.y));
    outv.z = f2bf(lrelu(av.z * bf2f(yv.z) + cv.z));
    outv.w = f2bf(lrelu(av.w * bf2f(yv.w) + cv.w));
  }
  *(u16x4*)(z + ((long)(b * SP + r)) * HH + i) = outv;
}

// ---------------- conv1d flat GEMM: PRODUCER-CONSUMER wave specialization ----
// The one untried structural lever (AITER's approach, guide §5/§Composed
// models: "producer-consumer wave specialization is the likely path past
// 36%"). All 11 prior variants had EVERY wave stage AND compute, so each
// wave's own vmcnt(0) drain (explicit or inside __syncthreads) blocked its
// own MFMA. Here: waves 0-3 = CONSUMERS (one 64x64 quadrant each, full
// K=1536, acc 4x4, issue ZERO VMEM in the loop -> __syncthreads' vmcnt(0)
// is free for them); waves 4-7 = PRODUCERS (stage tile t+1 into buf (t+1)&1,
// 8 gld_lds16/lane/step; their drain overlaps consumer MFMA). One
// __syncthreads per K-step (was 2); split-K reduction deleted (full-K acc).
// Buffers statically distinct by parity; producers write buf[(t+1)&1] while
// consumers read buf[t&1]; barrier at step end makes buf[(t+1)&1] ready and
// licenses overwrite of buf[t&1] at step t+1. Swizzle slot^(row&7) on both
// global source col and ds_read addr (2-way = free, 0 conflicts measured).
// XCD remap: one batch per XCD. Rule #20: all acc indices statically
// unrolled.
__global__ __launch_bounds__(512, 4) void k_conv(const u16* __restrict__ z,
                                                 const u16* __restrict__ wt,
                                                 const float* __restrict__ bias,
                                                 const int* __restrict__ lens,
                                                 u16* __restrict__ yout,
                                                 const float* __restrict__ resid,
                                                 float* __restrict__ fout,
                                                 float* __restrict__ sum,
                                                 float* __restrict__ sumsq) {
  __shared__ __align__(16) u16 L[2][2][BM * BK];   // [buf][A=0/B=1], 64 KB

  int nwg = gridDim.x;                        // 512, divisible by 8
  int bid = blockIdx.x;
  int t = (bid & 7) * (nwg >> 3) + (bid >> 3);
  int bn0 = (t % (HH / BN)) * BN; t /= (HH / BN);
  int bm0 = (t % (SS / BM)) * BM; t /= (SS / BM);
  int b = t;

  int tid = threadIdx.x;
  int wave = tid >> 6, lane = tid & 63;
  int wr = (wave >> 1) & 1, wc = wave & 1;    // consumer quadrant (waves 0-3)
  int l15 = lane & 15, l4 = lane >> 4;

  int t256 = tid & 255;                       // producer lane index (waves 4-7)
  int trow = t256 >> 3;                       // 0..31
  int tslot = t256 & 7;                       // 16B slot within 128B row

  const u16* zb = z + (size_t)b * SP * HH;
  int len = lens[b];

  floatx4 acc[4][4] = {};

  // producer: stage K-tile kt into buffer buf (A 128x64 + B 128x64)
  auto stage = [&](int buf, int kt) {
    int k0 = kt * BK;
    const u16* wkb = wt + (size_t)(k0 >> 9) * HH * HH + (k0 & 511);
    u16* dA = &L[buf][0][0];
    u16* dB = &L[buf][1][0];
#pragma unroll
    for (int rr = 0; rr < 4; rr++) {
      int r = rr * 32 + trow;
      int sc = (tslot ^ (r & 7)) * 8;
      gld_lds16(zb + (size_t)(bm0 + r) * HH + k0 + sc, dA + rr * 2048 + t256 * 8);
    }
#pragma unroll
    for (int rr = 0; rr < 4; rr++) {
      int r = rr * 32 + trow;
      int sc = (tslot ^ (r & 7)) * 8;
      gld_lds16(wkb + (size_t)(bn0 + r) * HH + sc, dB + rr * 2048 + t256 * 8);
    }
  };

  // consumer: one K-step of MFMA from buffer buf
  auto compute = [&](int buf) {
    const u16* sA = &L[buf][0][0];
    const u16* sB = &L[buf][1][0];
#pragma unroll
    for (int kk = 0; kk < 2; kk++) {
      short8 afr[4], bfr[4];
#pragma unroll
      for (int i = 0; i < 4; i++) {
        int ar = wr * 64 + i * 16 + l15;
        afr[i] = *(const short8*)&sA[ar * BK + (((kk * 4 + l4) ^ (ar & 7)) * 8)];
      }
#pragma unroll
      for (int j = 0; j < 4; j++) {
        int br = wc * 64 + j * 16 + l15;
        bfr[j] = *(const short8*)&sB[br * BK + (((kk * 4 + l4) ^ (br & 7)) * 8)];
      }
#pragma unroll
      for (int am = 0; am < 4; am++)
#pragma unroll
        for (int bn = 0; bn < 4; bn++)
          acc[am][bn] = __builtin_amdgcn_mfma_f32_16x16x32_bf16(afr[am], bfr[bn], acc[am][bn], 0, 0, 0);
    }
  };

  const int NT = 3 * HH / BK;                 // 24
  if (wave >= 4) stage(0, 0);
  __syncthreads();                            // producer drain; consumer free

  for (int kt = 0; kt < NT; kt++) {
    if (wave >= 4) {
      if (kt + 1 < NT) stage((kt + 1) & 1, kt + 1);
    } else {
      compute(kt & 1);
    }
    __syncthreads();                          // vmcnt(0) only costs producers
  }

  if (wave >= 4) return;                      // producers done (no more barriers)

  // ---- consumer epilogue: bias + mask + store (+ fused stats) ----
#pragma unroll
  for (int bn = 0; bn < 4; bn++) {
    int o = bn0 + wc * 64 + bn * 16 + l15;
    float bv = bias[o];
    float psum = 0.f, psq = 0.f;
#pragma unroll
    for (int am = 0; am < 4; am++) {
#pragma unroll
      for (int r = 0; r < 4; r++) {
        int s = bm0 + wr * 64 + am * 16 + l4 * 4 + r;
        float v = acc[am][bn][r] + bv;
        v = (s < len) ? v : 0.f;
        size_t off = ((size_t)(b * SS + s)) * HH + o;
        if (fout) {
          fout[off] = (v + resid[off]) * 0.70710678118654752f;
        } else {
          yout[off] = f2bf(v);
          psum += v;
          psq += v * v;
        }
      }
    }
    if (sum) {
      // masked rows contribute exactly 0; reduce over the 4 l4 lanes
      psum += __shfl_xor(psum, 16, 64);
      psum += __shfl_xor(psum, 32, 64);
      psq  += __shfl_xor(psq, 16, 64);
      psq  += __shfl_xor(psq, 32, 64);
      if (l4 == 0) {
        atomicAdd(&sum[b * HH + o], psum);
        atomicAdd(&sumsq[b * HH + o], psq);
      }
    }
  }
}

extern "C" void kernel_launch(void* const* d_in, const int* in_sizes, int n_in,
                              void* d_out, int out_size, void* d_ws, size_t ws_size,
                              hipStream_t stream) {
  const float* x    = (const float*)d_in[0];
  const float* sty  = (const float*)d_in[1];
  const int*   lens = (const int*)d_in[2];
  const float* p1w  = (const float*)d_in[3];
  const float* p1b  = (const float*)d_in[4];
  const float* p2w  = (const float*)d_in[5];
  const float* p2b  = (const float*)d_in[6];
  const float* c1v  = (const float*)d_in[7];
  const float* c1g  = (const float*)d_in[8];
  const float* c1b  = (const float*)d_in[9];
  const float* c2v  = (const float*)d_in[10];
  const float* c2g  = (const float*)d_in[11];
  const float* c2b  = (const float*)d_in[12];
  float* out = (float*)d_out;

  char* ws = (char*)d_ws;
  size_t cur = 0;
  auto alloc = [&](size_t bytes) {
    void* p = ws + cur;
    cur += (bytes + 255) & ~(size_t)255;
    return p;
  };
  u16*   wt1  = (u16*)alloc((size_t)3 * HH * HH * 2);
  u16*   wt2  = (u16*)alloc((size_t)3 * HH * HH * 2);
  float* g1   = (float*)alloc(NB * HH * 4);
  float* be1  = (float*)alloc(NB * HH * 4);
  float* g2   = (float*)alloc(NB * HH * 4);
  float* be2  = (float*)alloc(NB * HH * 4);
  float* sum1 = (float*)alloc(NB * HH * 4);
  float* sq1  = (float*)alloc(NB * HH * 4);
  float* sum2 = (float*)alloc(NB * HH * 4);
  float* sq2  = (float*)alloc(NB * HH * 4);
  u16*   z1   = (u16*)alloc((size_t)NB * SP * HH * 2);
  u16*   y1   = (u16*)alloc((size_t)NB * SS * HH * 2);
  u16*   z2   = (u16*)alloc((size_t)NB * SP * HH * 2);

  const int CGRID = NB * (SS / BM) * (HH / BN);   // 8*16*4 = 512

  // fused setup: wnorm (1024 blocks) + proj (64) + stats-zero (64)
  k_setup<<<2 * HH + 128, 256, 0, stream>>>(sty, p1w, p1b, p2w, p2b,
                                            c1v, c1g, c2v, c2g,
                                            wt1, wt2, g1, be1, g2, be2, sum1);

  // stage 1 stats over x
  k_stats_f32<<<NB * SSPLIT1, 256, 0, stream>>>(x, lens, sum1, sq1);

  // z1 = mask * lrelu(adain1(x))  [affine via per-block LDS table]
  k_prep_f32<<<NB * (SP * HH / 4 / 256), 256, 0, stream>>>(x, sum1, sq1, g1, be1,
                                                           lens, z1);

  // y1 = (conv1(z1) + b1) * mask (bf16), with fused stage-2 stats
  k_conv<<<CGRID, 512, 0, stream>>>(z1, wt1, c1b, lens, y1,
                                    nullptr, nullptr, sum2, sq2);

  // z2 = mask * lrelu(adain2(y1))  [affine via per-block LDS table]
  k_prep_bf16<<<NB * (SP * HH / 4 / 256), 256, 0, stream>>>(y1, sum2, sq2, g2, be2,
                                                            lens, z2);

  // out = ((conv2(z2) + b2) * mask + x) / sqrt(2)
  k_conv<<<CGRID, 512, 0, stream>>>(z2, wt2, c2b, lens, nullptr,
                                    x, out, nullptr, nullptr);
}

// Round 19
// 114.625 us; speedup vs baseline: 1.0405x; 1.0405x over previous
//
#include <hip/hip_runtime.h>

#define NB 8
#define SS 2048
#define HH 512
#define NSTY 128
#define SP (SS + 2)
#define EPSF 1e-5f

#define BM 128
#define BN 128
#define BK 64

typedef __attribute__((ext_vector_type(8))) short short8;
typedef __attribute__((ext_vector_type(4))) float floatx4;
typedef __attribute__((ext_vector_type(4))) unsigned short u16x4;
typedef unsigned short u16;

__device__ __forceinline__ float bf2f(u16 u) {
  union { float f; unsigned int i; } v; v.i = ((unsigned int)u) << 16; return v.f;
}
__device__ __forceinline__ u16 f2bf(float f) {
  union { float f; unsigned int i; } v; v.f = f;
  unsigned int x = v.i;
  return (u16)((x + 0x7fffu + ((x >> 16) & 1u)) >> 16);
}
__device__ __forceinline__ float lrelu(float v) { return v >= 0.f ? v : 0.2f * v; }

__device__ __forceinline__ void gld_lds16(const u16* g, u16* l) {
  __builtin_amdgcn_global_load_lds((const __attribute__((address_space(1))) void*)g,
                                   (__attribute__((address_space(3))) void*)l, 16, 0, 0);
}

// ---------------- fused setup: wnorm | proj | zero stats ----------------
__global__ void k_setup(const float* __restrict__ style,
                        const float* __restrict__ p1w, const float* __restrict__ p1b,
                        const float* __restrict__ p2w, const float* __restrict__ p2b,
                        const float* __restrict__ c1v, const float* __restrict__ c1g,
                        const float* __restrict__ c2v, const float* __restrict__ c2g,
                        u16* __restrict__ wt1, u16* __restrict__ wt2,
                        float* __restrict__ g1, float* __restrict__ be1,
                        float* __restrict__ g2, float* __restrict__ be2,
                        float* __restrict__ stats /* sum1 base, 4*NB*HH contig */) {
  int bid = blockIdx.x;
  if (bid < 2 * HH) {
    int o = bid % HH;
    int which = bid / HH;
    const float* v = which ? c2v : c1v;
    const float* g = which ? c2g : c1g;
    u16* wt = which ? wt2 : wt1;
    float s = 0.f;
    for (int e = threadIdx.x; e < HH * 3; e += 256) {
      float x = v[o * HH * 3 + e];
      s += x * x;
    }
    for (int off = 32; off > 0; off >>= 1) s += __shfl_down(s, off, 64);
    __shared__ float red[4];
    int wid = threadIdx.x >> 6, lane = threadIdx.x & 63;
    if (lane == 0) red[wid] = s;
    __syncthreads();
    float tot = red[0] + red[1] + red[2] + red[3];
    float scale = g[o] / sqrtf(tot);
    for (int e = threadIdx.x; e < HH * 3; e += 256) {
      int i = e / 3, k = e % 3;      // v[o][i][k] flat = o*1536 + e
      wt[(k * HH + o) * HH + i] = f2bf(v[o * HH * 3 + e] * scale);
    }
  } else if (bid < 2 * HH + 64) {
    int idx = (bid - 2 * HH) * 256 + threadIdx.x;
    int which = idx / (NB * 2 * HH);
    int r = idx % (NB * 2 * HH);
    int b = r / (2 * HH);
    int j = r % (2 * HH);
    const float* w = which ? p2w : p1w;
    const float* bias = which ? p2b : p1b;
    float acc = bias[j];
    const float* st = style + b * NSTY;
    const float* wr = w + j * NSTY;
    for (int t = 0; t < NSTY; t++) acc += st[t] * wr[t];
    float* gd = which ? g2 : g1;
    float* bd = which ? be2 : be1;
    if (j < HH) gd[b * HH + j] = acc;
    else        bd[b * HH + (j - HH)] = acc;
  } else {
    int i = (bid - 2 * HH - 64) * 256 + threadIdx.x;
    stats[i] = 0.f;
  }
}

// ---------------- masked stats over S (f32 input), latency-fixed ----------------
#define SSPLIT1 64
__global__ void k_stats_f32(const float* __restrict__ x, const int* __restrict__ lens,
                            float* __restrict__ sum, float* __restrict__ sumsq) {
  int b = blockIdx.x & 7;
  int chunk = blockIdx.x >> 3;                     // 0..63
  int s0 = chunk * (SS / SSPLIT1);                 // 32 rows per block
  int h4 = (threadIdx.x & 127) * 4;                // float4 column
  int sr = threadIdx.x >> 7;                       // 0,1
  int len = lens[b];
  float4 sm = {0.f, 0.f, 0.f, 0.f}, sq = {0.f, 0.f, 0.f, 0.f};
#pragma unroll
  for (int i = 0; i < 16; i++) {
    int s = s0 + i * 2 + sr;
    float4 v = *(const float4*)(x + ((long)(b * SS + s)) * HH + h4);
    float m = (s < len) ? 1.f : 0.f;
    v.x *= m; v.y *= m; v.z *= m; v.w *= m;
    sm.x += v.x; sm.y += v.y; sm.z += v.z; sm.w += v.w;
    sq.x += v.x * v.x; sq.y += v.y * v.y; sq.z += v.z * v.z; sq.w += v.w * v.w;
  }
  atomicAdd(&sum[b * HH + h4 + 0], sm.x);
  atomicAdd(&sum[b * HH + h4 + 1], sm.y);
  atomicAdd(&sum[b * HH + h4 + 2], sm.z);
  atomicAdd(&sum[b * HH + h4 + 3], sm.w);
  atomicAdd(&sumsq[b * HH + h4 + 0], sq.x);
  atomicAdd(&sumsq[b * HH + h4 + 1], sq.y);
  atomicAdd(&sumsq[b * HH + h4 + 2], sq.z);
  atomicAdd(&sumsq[b * HH + h4 + 3], sq.w);
}

// ---------------- adain affine from raw stats (inline helper) ----------------
__device__ __forceinline__ void affine4(const float* sum, const float* sumsq,
                                        const float* gam, const float* bet,
                                        int b, int i, float cnt,
                                        float4& av, float4& cv) {
  float4 sm = *(const float4*)(sum + b * HH + i);
  float4 sq = *(const float4*)(sumsq + b * HH + i);
  float4 gv = *(const float4*)(gam + b * HH + i);
  float4 bv = *(const float4*)(bet + b * HH + i);
  float rc = 1.f / cnt;
  float mx = sm.x * rc, my = sm.y * rc, mz = sm.z * rc, mw = sm.w * rc;
  av.x = (1.f + gv.x) * rsqrtf(sq.x * rc - mx * mx + EPSF);
  av.y = (1.f + gv.y) * rsqrtf(sq.y * rc - my * my + EPSF);
  av.z = (1.f + gv.z) * rsqrtf(sq.z * rc - mz * mz + EPSF);
  av.w = (1.f + gv.w) * rsqrtf(sq.w * rc - mw * mw + EPSF);
  cv.x = bv.x - mx * av.x;
  cv.y = bv.y - my * av.y;
  cv.z = bv.z - mz * av.z;
  cv.w = bv.w - mw * av.w;
}

// ---------------- Z prep (f32 src), fused affine, XCD-aligned ----------------
__global__ void k_prep_f32(const float* __restrict__ x,
                           const float* __restrict__ sum, const float* __restrict__ sumsq,
                           const float* __restrict__ gam, const float* __restrict__ bet,
                           const int* __restrict__ lens, u16* __restrict__ z) {
  int b = blockIdx.x & 7;
  int v = (blockIdx.x >> 3) * 256 + threadIdx.x;   // 0..262399 (exact)
  long off = (long)v * 4;                          // elem offset within batch
  int i = (int)(off % HH);
  int r = (int)(off / HH);                         // 0..SP-1
  int s = r - 1;
  int len = lens[b];
  u16x4 outv;
  if (s < 0 || s >= SS || s >= len) {
    outv = (u16x4){0, 0, 0, 0};
  } else {
    float4 av, cv;
    affine4(sum, sumsq, gam, bet, b, i, (float)len, av, cv);
    const float4 xv = *(const float4*)(x + ((long)(b * SS + s)) * HH + i);
    outv.x = f2bf(lrelu(av.x * xv.x + cv.x));
    outv.y = f2bf(lrelu(av.y * xv.y + cv.y));
    outv.z = f2bf(lrelu(av.z * xv.z + cv.z));
    outv.w = f2bf(lrelu(av.w * xv.w + cv.w));
  }
  *(u16x4*)(z + ((long)(b * SP + r)) * HH + i) = outv;
}

// ---------------- Z prep (bf16 src), fused affine, XCD-aligned ----------------
__global__ void k_prep_bf16(const u16* __restrict__ y,
                            const float* __restrict__ sum, const float* __restrict__ sumsq,
                            const float* __restrict__ gam, const float* __restrict__ bet,
                            const int* __restrict__ lens, u16* __restrict__ z) {
  int b = blockIdx.x & 7;
  int v = (blockIdx.x >> 3) * 256 + threadIdx.x;
  long off = (long)v * 4;
  int i = (int)(off % HH);
  int r = (int)(off / HH);
  int s = r - 1;
  int len = lens[b];
  u16x4 outv;
  if (s < 0 || s >= SS || s >= len) {
    outv = (u16x4){0, 0, 0, 0};
  } else {
    float4 av, cv;
    affine4(sum, sumsq, gam, bet, b, i, (float)len, av, cv);
    const u16x4 yv = *(const u16x4*)(y + ((long)(b * SS + s)) * HH + i);
    outv.x = f2bf(lrelu(av.x * bf2f(yv.x) + cv.x));
    outv.y = f2bf(lrelu(av.y * bf2f(yv.y) + cv.y));
    outv.z = f2bf(lrelu(av.z * bf2f(yv.z) + cv.z));
    outv.w = f2bf(lrelu(av.w * bf2f(yv.w) + cv.w));
  }
  *(u16x4*)(z + ((long)(b * SP + r)) * HH + i) = outv;
}

// ---------------- conv1d as flat GEMM: in-block split-K (session best) -------
// Minimum of 12 measured conv variants (44.5-45 us, MfmaUtil ~21%): 2 teams x
// 12 BK64 steps, drain-0 __syncthreads, 64 KB LDS, 2 blocks/CU (reg-capped
// 16 waves/CU: 64 acc AGPR + 64 arch VGPR). Bracketing: smaller wave tile
// loses on intensity (R13); counted-vmcnt/dbuf/fine-interleave regress
// (R4/R5/R11); producer-consumer role-split regresses (R18); setprio void
// (R16, rule #19); coop fusion catastrophic (R14). Per-step accounting
// (8.9k cyc ~ 1.2x serial phase sum) = the documented m97-class structural
// drain ceiling; breaking it needs asm-level scheduling, not HIP source.
// Rule #20: all post-loop acc indices are compile-time literals. Swizzle
// slot^(row&7) on both global source col and ds_read addr (0 conflicts).
// XCD remap: one batch per XCD (matches k_prep writers).
__global__ __launch_bounds__(512, 4) void k_conv(const u16* __restrict__ z,
                                                 const u16* __restrict__ wt,
                                                 const float* __restrict__ bias,
                                                 const int* __restrict__ lens,
                                                 u16* __restrict__ yout,
                                                 const float* __restrict__ resid,
                                                 float* __restrict__ fout,
                                                 float* __restrict__ sum,
                                                 float* __restrict__ sumsq) {
  __shared__ __align__(16) u16 L[2][2][BM * BK];

  int nwg = gridDim.x;                        // 512, divisible by 8
  int bid = blockIdx.x;
  int t = (bid & 7) * (nwg >> 3) + (bid >> 3);
  int bn0 = (t % (HH / BN)) * BN; t /= (HH / BN);
  int bm0 = (t % (SS / BM)) * BM; t /= (SS / BM);
  int b = t;

  int tid = threadIdx.x;
  int wave = tid >> 6, lane = tid & 63;
  int team = wave >> 2;
  int tw = wave & 3;
  int wr = tw >> 1, wc = tw & 1;
  int l15 = lane & 15, l4 = lane >> 4;

  int t256 = tid & 255;
  int trow = t256 >> 3;
  int tslot = t256 & 7;

  u16* LA = &L[team][0][0];
  u16* LB = &L[team][1][0];

  const u16* zb = z + (size_t)b * SP * HH;
  int len = lens[b];
  int kt0 = team * 12;

  floatx4 acc[4][4] = {};

  for (int kt = 0; kt < 12; kt++) {
    int k0 = (kt0 + kt) * BK;
    const u16* wkb = wt + (size_t)(k0 >> 9) * HH * HH + (k0 & 511);
#pragma unroll
    for (int rr = 0; rr < 4; rr++) {
      int r = rr * 32 + trow;
      int sc = (tslot ^ (r & 7)) * 8;
      gld_lds16(zb + (size_t)(bm0 + r) * HH + k0 + sc, LA + rr * 2048 + t256 * 8);
    }
#pragma unroll
    for (int rr = 0; rr < 4; rr++) {
      int r = rr * 32 + trow;
      int sc = (tslot ^ (r & 7)) * 8;
      gld_lds16(wkb + (size_t)(bn0 + r) * HH + sc, LB + rr * 2048 + t256 * 8);
    }
    __syncthreads();
#pragma unroll
    for (int kk = 0; kk < 2; kk++) {
      short8 afr[4], bfr[4];
#pragma unroll
      for (int i = 0; i < 4; i++) {
        int ar = wr * 64 + i * 16 + l15;
        afr[i] = *(const short8*)&LA[ar * BK + (((kk * 4 + l4) ^ (ar & 7)) * 8)];
      }
#pragma unroll
      for (int j = 0; j < 4; j++) {
        int br = wc * 64 + j * 16 + l15;
        bfr[j] = *(const short8*)&LB[br * BK + (((kk * 4 + l4) ^ (br & 7)) * 8)];
      }
#pragma unroll
      for (int am = 0; am < 4; am++)
#pragma unroll
        for (int bn = 0; bn < 4; bn++)
          acc[am][bn] = __builtin_amdgcn_mfma_f32_16x16x32_bf16(afr[am], bfr[bn], acc[am][bn], 0, 0, 0);
    }
    __syncthreads();
  }

  floatx4* scr = (floatx4*)&L[0][0][0];
  floatx4* my = scr + (size_t)team * 2048;
  if (team == 0) {
#pragma unroll
    for (int am = 0; am < 4; am++) {
      my[(am * 2 + 0) * 256 + t256] = acc[am][2];
      my[(am * 2 + 1) * 256 + t256] = acc[am][3];
    }
  } else {
#pragma unroll
    for (int am = 0; am < 4; am++) {
      my[(am * 2 + 0) * 256 + t256] = acc[am][0];
      my[(am * 2 + 1) * 256 + t256] = acc[am][1];
    }
  }
  __syncthreads();
  const floatx4* other = scr + (size_t)(team ^ 1) * 2048;
  if (team == 0) {
#pragma unroll
    for (int am = 0; am < 4; am++) {
      acc[am][0] += other[(am * 2 + 0) * 256 + t256];
      acc[am][1] += other[(am * 2 + 1) * 256 + t256];
    }
  } else {
#pragma unroll
    for (int am = 0; am < 4; am++) {
      acc[am][2] += other[(am * 2 + 0) * 256 + t256];
      acc[am][3] += other[(am * 2 + 1) * 256 + t256];
    }
  }

#define EPI(BN_) do {                                                        \
    int o = bn0 + wc * 64 + (BN_) * 16 + l15;                                \
    float bv = bias[o];                                                      \
    float psum = 0.f, psq = 0.f;                                             \
    _Pragma("unroll")                                                        \
    for (int am = 0; am < 4; am++) {                                         \
      _Pragma("unroll")                                                      \
      for (int r = 0; r < 4; r++) {                                          \
        int s = bm0 + wr * 64 + am * 16 + l4 * 4 + r;                        \
        float v = acc[am][BN_][r] + bv;                                      \
        v = (s < len) ? v : 0.f;                                             \
        size_t off = ((size_t)(b * SS + s)) * HH + o;                        \
        if (fout) {                                                          \
          fout[off] = (v + resid[off]) * 0.70710678118654752f;               \
        } else {                                                             \
          yout[off] = f2bf(v);                                               \
          psum += v;                                                         \
          psq += v * v;                                                      \
        }                                                                    \
      }                                                                      \
    }                                                                        \
    if (sum) {                                                               \
      psum += __shfl_xor(psum, 16, 64);                                      \
      psum += __shfl_xor(psum, 32, 64);                                      \
      psq  += __shfl_xor(psq, 16, 64);                                       \
      psq  += __shfl_xor(psq, 32, 64);                                       \
      if (l4 == 0) {                                                         \
        atomicAdd(&sum[b * HH + o], psum);                                   \
        atomicAdd(&sumsq[b * HH + o], psq);                                  \
      }                                                                      \
    }                                                                        \
  } while (0)

  if (team == 0) { EPI(0); EPI(1); }
  else           { EPI(2); EPI(3); }
#undef EPI
}

extern "C" void kernel_launch(void* const* d_in, const int* in_sizes, int n_in,
                              void* d_out, int out_size, void* d_ws, size_t ws_size,
                              hipStream_t stream) {
  const float* x    = (const float*)d_in[0];
  const float* sty  = (const float*)d_in[1];
  const int*   lens = (const int*)d_in[2];
  const float* p1w  = (const float*)d_in[3];
  const float* p1b  = (const float*)d_in[4];
  const float* p2w  = (const float*)d_in[5];
  const float* p2b  = (const float*)d_in[6];
  const float* c1v  = (const float*)d_in[7];
  const float* c1g  = (const float*)d_in[8];
  const float* c1b  = (const float*)d_in[9];
  const float* c2v  = (const float*)d_in[10];
  const float* c2g  = (const float*)d_in[11];
  const float* c2b  = (const float*)d_in[12];
  float* out = (float*)d_out;

  char* ws = (char*)d_ws;
  size_t cur = 0;
  auto alloc = [&](size_t bytes) {
    void* p = ws + cur;
    cur += (bytes + 255) & ~(size_t)255;
    return p;
  };
  u16*   wt1  = (u16*)alloc((size_t)3 * HH * HH * 2);
  u16*   wt2  = (u16*)alloc((size_t)3 * HH * HH * 2);
  float* g1   = (float*)alloc(NB * HH * 4);
  float* be1  = (float*)alloc(NB * HH * 4);
  float* g2   = (float*)alloc(NB * HH * 4);
  float* be2  = (float*)alloc(NB * HH * 4);
  float* sum1 = (float*)alloc(NB * HH * 4);
  float* sq1  = (float*)alloc(NB * HH * 4);
  float* sum2 = (float*)alloc(NB * HH * 4);
  float* sq2  = (float*)alloc(NB * HH * 4);
  u16*   z1   = (u16*)alloc((size_t)NB * SP * HH * 2);
  u16*   y1   = (u16*)alloc((size_t)NB * SS * HH * 2);
  u16*   z2   = (u16*)alloc((size_t)NB * SP * HH * 2);

  const int CGRID = NB * (SS / BM) * (HH / BN);   // 8*16*4 = 512

  // fused setup: wnorm (1024 blocks) + proj (64) + stats-zero (64)
  k_setup<<<2 * HH + 128, 256, 0, stream>>>(sty, p1w, p1b, p2w, p2b,
                                            c1v, c1g, c2v, c2g,
                                            wt1, wt2, g1, be1, g2, be2, sum1);

  // stage 1 stats over x
  k_stats_f32<<<NB * SSPLIT1, 256, 0, stream>>>(x, lens, sum1, sq1);

  // z1 = mask * lrelu(adain1(x))  [affine fused from raw stats]
  k_prep_f32<<<NB * (SP * HH / 4 / 256), 256, 0, stream>>>(x, sum1, sq1, g1, be1,
                                                           lens, z1);

  // y1 = (conv1(z1) + b1) * mask (bf16), with fused stage-2 stats
  k_conv<<<CGRID, 512, 0, stream>>>(z1, wt1, c1b, lens, y1,
                                    nullptr, nullptr, sum2, sq2);

  // z2 = mask * lrelu(adain2(y1))  [affine fused from raw stats]
  k_prep_bf16<<<NB * (SP * HH / 4 / 256), 256, 0, stream>>>(y1, sum2, sq2, g2, be2,
                                                            lens, z2);

  // out = ((conv2(z2) + b2) * mask + x) / sqrt(2)
  k_conv<<<CGRID, 512, 0, stream>>>(z2, wt2, c2b, lens, nullptr,
                                    x, out, nullptr, nullptr);
}